// Round 14
// baseline (200.072 us; speedup 1.0000x reference)
//
#include <hip/hip_runtime.h>
#include <hip/hip_bf16.h>

#define NV 100000
#define NE 1600000
#define NB 2
#define FIN 32
#define NK 4
#define FOUT 32

#define RPB 128                          // rows per bucket
#define NBUCK ((NV + RPB - 1) / RPB)     // 782
#define SLAB 2816                        // slab capacity (mean padded 2494, ~6 sigma slack)
#define CHUNK 8192                       // edges per block in place pass (196 blocks x 1024 thr)

typedef long long ll;

// ---------------- fallback (round-0) kernels ----------------

__global__ void scale_init_kernel(float* __restrict__ dst, const float* __restrict__ src,
                                  float alpha, int n) {
    int i = blockIdx.x * blockDim.x + threadIdx.x;
    if (i < n) dst[i] = alpha * src[i];
}

__global__ void spmm_scatter_kernel(float* __restrict__ y, const float* __restrict__ x,
                                    const int* __restrict__ rows, const int* __restrict__ cols,
                                    const float* __restrict__ vals, float scale) {
    long tid = (long)blockIdx.x * blockDim.x + threadIdx.x;
    int e = (int)(tid >> 5);
    int f = (int)(tid & 31);
    if (e >= NE) return;
    int r = rows[e];
    int c = cols[e];
    float v = scale * vals[e];
#pragma unroll
    for (int b = 0; b < NB; ++b) {
        float g = x[(long)b * NV * FIN + (long)c * FIN + f];
        atomicAdd(&y[(long)b * NV * FIN + (long)r * FIN + f], v * g);
    }
}

__global__ void term_gemm_kernel(float* __restrict__ out, const float* __restrict__ x,
                                 const float* __restrict__ weight, const float* __restrict__ bias,
                                 int k, int first) {
    __shared__ float Wl[FIN][FOUT];
    __shared__ float Xl[8][FIN];
    int tid = threadIdx.x;
    for (int i = tid; i < FIN * FOUT; i += 256) {
        int f = i >> 5, o = i & 31;
        Wl[f][o] = weight[f * (NK * FOUT) + k * FOUT + o];
    }
    long rbase = (long)blockIdx.x * 8;
    for (int i = tid; i < 8 * FIN; i += 256) {
        int rv = i >> 5, f = i & 31;
        Xl[rv][f] = x[(rbase + rv) * FIN + f];
    }
    __syncthreads();
    int rv = tid >> 5, o = tid & 31;
    float acc = 0.f;
#pragma unroll
    for (int f = 0; f < FIN; ++f) acc += Xl[rv][f] * Wl[f][o];
    long r = rbase + rv;
    if (first) out[r * FOUT + o] = acc + bias[o];
    else       out[r * FOUT + o] += acc;
}

// ---------------- slab CSR build ----------------
// edge record (8B): bits 0..16 = col, bits 17..23 = row-within-bucket, high 32 = val bits

__global__ __launch_bounds__(1024)
void bucket_place_kernel(const int* __restrict__ rows, const int* __restrict__ cols,
                         const float* __restrict__ vals, int* __restrict__ gcursor,
                         ll* __restrict__ edges) {
    __shared__ int cnt[NBUCK];
    __shared__ int cur[NBUCK];
    for (int i = threadIdx.x; i < NBUCK; i += 1024) cnt[i] = 0;
    __syncthreads();
    long base = (long)blockIdx.x * CHUNK;
    int lim = (base + CHUNK <= NE) ? CHUNK : (int)(NE - base);
    for (int i = threadIdx.x; i < lim; i += 1024)
        atomicAdd(&cnt[rows[base + i] >> 7], 1);
    __syncthreads();
    // reserve a contiguous range per bucket for this block
    for (int i = threadIdx.x; i < NBUCK; i += 1024)
        cur[i] = cnt[i] ? atomicAdd(&gcursor[i], cnt[i]) : 0;
    __syncthreads();
    if (lim == CHUNK) {
        // fast path: 8 edges/thread, batch atomics so their latency overlaps
        int bb[8]; ll rec[8]; int pos[8];
#pragma unroll
        for (int u = 0; u < 8; ++u) {
            int i = threadIdx.x + u * 1024;
            int r = rows[base + i];
            bb[u] = r >> 7;
            unsigned int lo = ((unsigned int)cols[base + i]) | (((unsigned int)(r & 127)) << 17);
            unsigned int hi = __float_as_uint(vals[base + i]);
            rec[u] = (ll)lo | ((ll)hi << 32);
        }
#pragma unroll
        for (int u = 0; u < 8; ++u) pos[u] = atomicAdd(&cur[bb[u]], 1);
#pragma unroll
        for (int u = 0; u < 8; ++u)
            if (pos[u] < (bb[u] + 1) * SLAB) edges[pos[u]] = rec[u];
    } else {
        for (int i = threadIdx.x; i < lim; i += 1024) {
            int r = rows[base + i];
            int b = r >> 7;
            unsigned int lo = ((unsigned int)cols[base + i]) | (((unsigned int)(r & 127)) << 17);
            unsigned int hi = __float_as_uint(vals[base + i]);
            int pos = atomicAdd(&cur[b], 1);
            if (pos < (b + 1) * SLAB) edges[pos] = (ll)lo | ((ll)hi << 32);
        }
    }
}

// LDS-staged in-place counting sort by row-within-bucket; pads each row's list to a
// multiple of 8 with zero-val records; emits row_start/counts (padded counts)
__global__ __launch_bounds__(512)
void bucket_sort_kernel(ll* __restrict__ edges, const int* __restrict__ gcursor,
                        int* __restrict__ row_start, int* __restrict__ counts) {
    __shared__ ll recL[SLAB];                       // 22 KB
    __shared__ int rcnt[RPB];
    __shared__ int pcnt[RPB];
    __shared__ int rcur[RPB];
    __shared__ int ssc[RPB];
    int b = blockIdx.x;
    int base = b * SLAB;
    int n = gcursor[b] - base;
    if (n > SLAB) n = SLAB;
    if (n < 0) n = 0;
    int t = threadIdx.x;
    if (t < RPB) rcnt[t] = 0;
    __syncthreads();
    for (int i = t; i < n; i += 512) {
        ll rec = edges[base + i];
        recL[i] = rec;
        atomicAdd(&rcnt[(int)((rec >> 17) & 127)], 1);
    }
    __syncthreads();
    if (t < RPB) pcnt[t] = (rcnt[t] + 7) & ~7;      // pad to multiple of 8
    __syncthreads();
    // inclusive scan of pcnt
    if (t < RPB) ssc[t] = pcnt[t];
    __syncthreads();
    for (int off = 1; off < RPB; off <<= 1) {
        int x = 0;
        if (t < RPB && t >= off) x = ssc[t - off];
        __syncthreads();
        if (t < RPB) ssc[t] += x;
        __syncthreads();
    }
    if (ssc[RPB - 1] > SLAB) {                      // overflow: fall back to unpadded
        __syncthreads();
        if (t < RPB) { pcnt[t] = rcnt[t]; ssc[t] = rcnt[t]; }
        __syncthreads();
        for (int off = 1; off < RPB; off <<= 1) {
            int x = 0;
            if (t < RPB && t >= off) x = ssc[t - off];
            __syncthreads();
            if (t < RPB) ssc[t] += x;
            __syncthreads();
        }
    }
    __syncthreads();
    if (t < RPB) {
        int ex = ssc[t] - pcnt[t];                  // exclusive (padded) start
        rcur[t] = ex;
        int v = b * RPB + t;
        if (v < NV) { row_start[v] = base + ex; counts[v] = pcnt[t]; }
    }
    __syncthreads();
    for (int i = t; i < n; i += 512) {
        ll rec = recL[i];
        int pos = atomicAdd(&rcur[(int)((rec >> 17) & 127)], 1);
        edges[base + pos] = rec;
    }
    __syncthreads();
    // fill pad slots with zero records (col=0, val=0)
    if (t < RPB) {
        int start = ssc[t] - pcnt[t];
        for (int i = rcnt[t]; i < pcnt[t]; ++i)
            edges[base + start + i] = 0;
    }
}

// ---------------- bf16 conversion: inputs [B,V,F] -> xb [V, B*32] ----------------
// block 0 additionally initializes the slab cursors (runs before place in stream order)
__global__ void convert_x0_kernel(__hip_bfloat16* __restrict__ xb, const float* __restrict__ inputs,
                                  int* __restrict__ gcursor) {
    if (blockIdx.x == 0) {
        for (int i = threadIdx.x; i < NBUCK; i += 256) gcursor[i] = i * SLAB;
    }
    long i = (long)blockIdx.x * blockDim.x + threadIdx.x;
    if (i >= (long)NV * 64) return;
    int lane = (int)(i & 63);
    long v = i >> 6;
    int b = lane >> 5, f = lane & 31;
    xb[i] = __float2bfloat16(inputs[(long)b * NV * FIN + v * FIN + f]);
}

// ---------------- gather SpMM with fused recursion (bf16) ----------------
// one wave per row; 4 x 16-lane groups each handle one edge per gather instruction:
// lane (grp, l16) loads uint2 = features [4*l16, 4*l16+4) of edge (j + grp).
// 4x memory-level parallelism per vmem instruction vs the 1-edge/instr version.
__global__ __launch_bounds__(256)
void spmm_gather_kernel(__hip_bfloat16* __restrict__ xnext, const __hip_bfloat16* __restrict__ xcur,
                        const __hip_bfloat16* __restrict__ xprev,
                        const int* __restrict__ row_start, const int* __restrict__ counts,
                        const ll* __restrict__ edges, float alpha, float beta) {
    int r = blockIdx.x * 4 + (threadIdx.x >> 6);
    int lane = threadIdx.x & 63;
    int grp = lane >> 4;
    int l16 = lane & 15;
    int s = __builtin_amdgcn_readfirstlane(row_start[r]);
    int cnt = __builtin_amdgcn_readfirstlane(counts[r]);
    const ll* ep = edges + s;
    const unsigned int* xu = (const unsigned int*)xcur;   // [V][32] uints
    float ax = 0.f, ay = 0.f, az = 0.f, aw = 0.f;
    int j = 0;
    for (; j + 16 <= cnt; j += 16) {                      // 16 edges: 4 gathers, 4 in flight each
        ll e[4]; uint2 g[4];
#pragma unroll
        for (int u = 0; u < 4; ++u) e[u] = ep[j + 4 * u + grp];
#pragma unroll
        for (int u = 0; u < 4; ++u)
            g[u] = *(const uint2*)(xu + (unsigned int)(e[u] & 0x1FFFF) * 32u + l16 * 2);
#pragma unroll
        for (int u = 0; u < 4; ++u) {
            float v = __uint_as_float((unsigned int)((unsigned long long)e[u] >> 32));
            ax = fmaf(v, __uint_as_float(g[u].x << 16), ax);
            ay = fmaf(v, __uint_as_float(g[u].x & 0xffff0000u), ay);
            az = fmaf(v, __uint_as_float(g[u].y << 16), az);
            aw = fmaf(v, __uint_as_float(g[u].y & 0xffff0000u), aw);
        }
    }
    if (j + 8 <= cnt) {                                   // pad-to-8 remainder
        ll e[2]; uint2 g[2];
#pragma unroll
        for (int u = 0; u < 2; ++u) e[u] = ep[j + 4 * u + grp];
#pragma unroll
        for (int u = 0; u < 2; ++u)
            g[u] = *(const uint2*)(xu + (unsigned int)(e[u] & 0x1FFFF) * 32u + l16 * 2);
#pragma unroll
        for (int u = 0; u < 2; ++u) {
            float v = __uint_as_float((unsigned int)((unsigned long long)e[u] >> 32));
            ax = fmaf(v, __uint_as_float(g[u].x << 16), ax);
            ay = fmaf(v, __uint_as_float(g[u].x & 0xffff0000u), ay);
            az = fmaf(v, __uint_as_float(g[u].y << 16), az);
            aw = fmaf(v, __uint_as_float(g[u].y & 0xffff0000u), aw);
        }
        j += 8;
    }
    for (; j < cnt; j += 4) {                             // unpadded fallback only
        int idx = j + grp;
        bool valid = idx < cnt;
        ll e0 = ep[valid ? idx : (cnt - 1)];
        uint2 g0 = *(const uint2*)(xu + (unsigned int)(e0 & 0x1FFFF) * 32u + l16 * 2);
        float v = valid ? __uint_as_float((unsigned int)((unsigned long long)e0 >> 32)) : 0.f;
        ax = fmaf(v, __uint_as_float(g0.x << 16), ax);
        ay = fmaf(v, __uint_as_float(g0.x & 0xffff0000u), ay);
        az = fmaf(v, __uint_as_float(g0.y << 16), az);
        aw = fmaf(v, __uint_as_float(g0.y & 0xffff0000u), aw);
    }
    // combine the 4 groups (lane bits 4 and 5)
    ax += __shfl_xor(ax, 16); ax += __shfl_xor(ax, 32);
    ay += __shfl_xor(ay, 16); ay += __shfl_xor(ay, 32);
    az += __shfl_xor(az, 16); az += __shfl_xor(az, 32);
    aw += __shfl_xor(aw, 16); aw += __shfl_xor(aw, 32);
    if (lane < 16) {
        float rx = alpha * ax, ry = alpha * ay, rz = alpha * az, rw = alpha * aw;
        if (beta != 0.f) {
            uint2 p = *(const uint2*)((const unsigned int*)xprev + (long)r * 32 + l16 * 2);
            rx += beta * __uint_as_float(p.x << 16);
            ry += beta * __uint_as_float(p.x & 0xffff0000u);
            rz += beta * __uint_as_float(p.y << 16);
            rw += beta * __uint_as_float(p.y & 0xffff0000u);
        }
        __hip_bfloat16 o0 = __float2bfloat16(rx), o1 = __float2bfloat16(ry);
        __hip_bfloat16 o2 = __float2bfloat16(rz), o3 = __float2bfloat16(rw);
        uint2 st;
        st.x = (unsigned int)*(unsigned short*)&o0 | ((unsigned int)*(unsigned short*)&o1 << 16);
        st.y = (unsigned int)*(unsigned short*)&o2 | ((unsigned int)*(unsigned short*)&o3 << 16);
        *(uint2*)((unsigned int*)xnext + (long)r * 32 + l16 * 2) = st;
    }
}

// ---------------- fused final einsum: out = bias + sum_k xk @ W[:,k,:] ----------------
// grid (x = (v,b) / 256, y = output half); thread = (v,b), 16 outputs, 64B line write
__global__ __launch_bounds__(256)
void final_gemm_kernel(float* __restrict__ out,
                       const __hip_bfloat16* __restrict__ xb0,
                       const __hip_bfloat16* __restrict__ xb1,
                       const __hip_bfloat16* __restrict__ xb2,
                       const __hip_bfloat16* __restrict__ xb3,
                       const float* __restrict__ weight,
                       const float* __restrict__ bias) {
    int t = blockIdx.x * blockDim.x + threadIdx.x;
    if (t >= NV * NB) return;
    int oh = blockIdx.y * 16;            // output half offset
    int v = t >> 1, b = t & 1;
    float acc[16];
#pragma unroll
    for (int o = 0; o < 16; ++o) acc[o] = bias[oh + o];
    for (int k = 0; k < NK; ++k) {
        const __hip_bfloat16* xr = (k == 0) ? xb0 : (k == 1) ? xb1 : (k == 2) ? xb2 : xb3;
        const uint4* xp = (const uint4*)(xr + (long)v * 64 + b * 32);
        uint4 q0 = xp[0], q1 = xp[1], q2 = xp[2], q3 = xp[3];
        unsigned int qq[16] = {q0.x, q0.y, q0.z, q0.w, q1.x, q1.y, q1.z, q1.w,
                               q2.x, q2.y, q2.z, q2.w, q3.x, q3.y, q3.z, q3.w};
        const float* wk = weight + k * FOUT + oh;
#pragma unroll
        for (int i = 0; i < 16; ++i) {
            float xlo = __uint_as_float(qq[i] << 16);
            float xhi = __uint_as_float(qq[i] & 0xffff0000u);
            const float* w0 = wk + (2 * i) * (NK * FOUT);
            const float* w1 = wk + (2 * i + 1) * (NK * FOUT);
#pragma unroll
            for (int o = 0; o < 16; ++o) {
                acc[o] = fmaf(xlo, w0[o], acc[o]);
                acc[o] = fmaf(xhi, w1[o], acc[o]);
            }
        }
    }
    float* op = out + (long)b * NV * FOUT + (long)v * FOUT + oh;
#pragma unroll
    for (int o = 0; o < 16; ++o) op[o] = acc[o];
}

extern "C" void kernel_launch(void* const* d_in, const int* in_sizes, int n_in,
                              void* d_out, int out_size, void* d_ws, size_t ws_size,
                              hipStream_t stream) {
    const float* inputs = (const float*)d_in[0];
    const int*   rows   = (const int*)d_in[1];
    const int*   cols   = (const int*)d_in[2];
    const float* vals   = (const float*)d_in[3];
    const float* weight = (const float*)d_in[4];
    const float* bias   = (const float*)d_in[5];
    float* out = (float*)d_out;

    const long n = (long)NB * NV * FIN;            // 6.4M
    const int gG = (NB * NV) / 8;
    const int gChunk = (NE + CHUNK - 1) / CHUNK;   // 196
    const int gRow = NV / 4;                       // 25000 (4 waves/block, 1 row/wave)
    const int gConv = (int)(((long)NV * 64 + 255) / 256);
    const int gGemm = (NV * NB + 255) / 256;       // 782

    // ws layout: [gcursor 1024][row_start NV][counts NV] [edges NBUCK*SLAB] [xb0..xb3]
    int* gcursor   = (int*)d_ws;                   // [1024]
    int* row_start = gcursor + 1024;               // [NV]
    int* counts    = row_start + NV;               // [NV]
    ll* edges      = (ll*)(counts + NV);           // [NBUCK*SLAB]
    size_t off = (size_t)((char*)(edges + (long)NBUCK * SLAB) - (char*)d_ws);
    off = (off + 255) & ~(size_t)255;
    __hip_bfloat16* xb0 = (__hip_bfloat16*)((char*)d_ws + off);
    __hip_bfloat16* xb1 = xb0 + (long)NV * 64;
    __hip_bfloat16* xb2 = xb1 + (long)NV * 64;
    __hip_bfloat16* xb3 = xb2 + (long)NV * 64;
    size_t need = off + 4 * (size_t)NV * 64 * sizeof(__hip_bfloat16);

    if (ws_size < need) {
        // fallback: round-0 atomic scatter path
        float* fA = (float*)d_ws;
        float* fB = fA + n;
        const int gNf = (int)((n + 255) / 256);
        const int gEf = (NE * 32 + 255) / 256;
        term_gemm_kernel<<<gG, 256, 0, stream>>>(out, inputs, weight, bias, 0, 1);
        scale_init_kernel<<<gNf, 256, 0, stream>>>(fA, inputs, 0.f, (int)n);
        spmm_scatter_kernel<<<gEf, 256, 0, stream>>>(fA, inputs, rows, cols, vals, 1.f);
        term_gemm_kernel<<<gG, 256, 0, stream>>>(out, fA, weight, bias, 1, 0);
        scale_init_kernel<<<gNf, 256, 0, stream>>>(fB, inputs, -1.f, (int)n);
        spmm_scatter_kernel<<<gEf, 256, 0, stream>>>(fB, fA, rows, cols, vals, 2.f);
        term_gemm_kernel<<<gG, 256, 0, stream>>>(out, fB, weight, bias, 2, 0);
        scale_init_kernel<<<gNf, 256, 0, stream>>>(fA, fA, -1.f, (int)n);
        spmm_scatter_kernel<<<gEf, 256, 0, stream>>>(fA, fB, rows, cols, vals, 2.f);
        term_gemm_kernel<<<gG, 256, 0, stream>>>(out, fA, weight, bias, 3, 0);
        return;
    }

    // convert first (block 0 also inits slab cursors), then slab CSR build
    convert_x0_kernel<<<gConv, 256, 0, stream>>>(xb0, inputs, gcursor);
    bucket_place_kernel<<<gChunk, 1024, 0, stream>>>(rows, cols, vals, gcursor, edges);
    bucket_sort_kernel<<<NBUCK, 512, 0, stream>>>(edges, gcursor, row_start, counts);

    // recursion
    spmm_gather_kernel<<<gRow, 256, 0, stream>>>(xb1, xb0, nullptr, row_start, counts,
                                                 edges, 1.f, 0.f);
    spmm_gather_kernel<<<gRow, 256, 0, stream>>>(xb2, xb1, xb0, row_start, counts,
                                                 edges, 2.f, -1.f);
    spmm_gather_kernel<<<gRow, 256, 0, stream>>>(xb3, xb2, xb1, row_start, counts,
                                                 edges, 2.f, -1.f);

    // fused einsum over all 4 terms (y-dim splits the 32 outputs into two halves)
    final_gemm_kernel<<<dim3(gGemm, 2), 256, 0, stream>>>(out, xb0, xb1, xb2, xb3,
                                                          weight, bias);
}

// Round 15
// 184.202 us; speedup vs baseline: 1.0862x; 1.0862x over previous
//
#include <hip/hip_runtime.h>
#include <hip/hip_bf16.h>

#define NV 100000
#define NE 1600000
#define NB 2
#define FIN 32
#define NK 4
#define FOUT 32

#define RPB 128                          // rows per bucket
#define NBUCK ((NV + RPB - 1) / RPB)     // 782
#define SLAB 2816                        // slab capacity (mean padded 2494, ~6 sigma slack)
#define CHUNK 8192                       // edges per block in place pass (196 blocks x 1024 thr)

typedef long long ll;

// ---------------- fallback (round-0) kernels ----------------

__global__ void scale_init_kernel(float* __restrict__ dst, const float* __restrict__ src,
                                  float alpha, int n) {
    int i = blockIdx.x * blockDim.x + threadIdx.x;
    if (i < n) dst[i] = alpha * src[i];
}

__global__ void spmm_scatter_kernel(float* __restrict__ y, const float* __restrict__ x,
                                    const int* __restrict__ rows, const int* __restrict__ cols,
                                    const float* __restrict__ vals, float scale) {
    long tid = (long)blockIdx.x * blockDim.x + threadIdx.x;
    int e = (int)(tid >> 5);
    int f = (int)(tid & 31);
    if (e >= NE) return;
    int r = rows[e];
    int c = cols[e];
    float v = scale * vals[e];
#pragma unroll
    for (int b = 0; b < NB; ++b) {
        float g = x[(long)b * NV * FIN + (long)c * FIN + f];
        atomicAdd(&y[(long)b * NV * FIN + (long)r * FIN + f], v * g);
    }
}

__global__ void term_gemm_kernel(float* __restrict__ out, const float* __restrict__ x,
                                 const float* __restrict__ weight, const float* __restrict__ bias,
                                 int k, int first) {
    __shared__ float Wl[FIN][FOUT];
    __shared__ float Xl[8][FIN];
    int tid = threadIdx.x;
    for (int i = tid; i < FIN * FOUT; i += 256) {
        int f = i >> 5, o = i & 31;
        Wl[f][o] = weight[f * (NK * FOUT) + k * FOUT + o];
    }
    long rbase = (long)blockIdx.x * 8;
    for (int i = tid; i < 8 * FIN; i += 256) {
        int rv = i >> 5, f = i & 31;
        Xl[rv][f] = x[(rbase + rv) * FIN + f];
    }
    __syncthreads();
    int rv = tid >> 5, o = tid & 31;
    float acc = 0.f;
#pragma unroll
    for (int f = 0; f < FIN; ++f) acc += Xl[rv][f] * Wl[f][o];
    long r = rbase + rv;
    if (first) out[r * FOUT + o] = acc + bias[o];
    else       out[r * FOUT + o] += acc;
}

// ---------------- slab CSR build ----------------
// edge record (8B): bits 0..16 = col, bits 17..23 = row-within-bucket, high 32 = val bits

__global__ __launch_bounds__(1024)
void bucket_place_kernel(const int* __restrict__ rows, const int* __restrict__ cols,
                         const float* __restrict__ vals, int* __restrict__ gcursor,
                         ll* __restrict__ edges) {
    __shared__ int cnt[NBUCK];
    __shared__ int cur[NBUCK];
    for (int i = threadIdx.x; i < NBUCK; i += 1024) cnt[i] = 0;
    __syncthreads();
    long base = (long)blockIdx.x * CHUNK;
    int lim = (base + CHUNK <= NE) ? CHUNK : (int)(NE - base);
    for (int i = threadIdx.x; i < lim; i += 1024)
        atomicAdd(&cnt[rows[base + i] >> 7], 1);
    __syncthreads();
    // reserve a contiguous range per bucket for this block
    for (int i = threadIdx.x; i < NBUCK; i += 1024)
        cur[i] = cnt[i] ? atomicAdd(&gcursor[i], cnt[i]) : 0;
    __syncthreads();
    if (lim == CHUNK) {
        // fast path: 8 edges/thread, batch atomics so their latency overlaps
        int bb[8]; ll rec[8]; int pos[8];
#pragma unroll
        for (int u = 0; u < 8; ++u) {
            int i = threadIdx.x + u * 1024;
            int r = rows[base + i];
            bb[u] = r >> 7;
            unsigned int lo = ((unsigned int)cols[base + i]) | (((unsigned int)(r & 127)) << 17);
            unsigned int hi = __float_as_uint(vals[base + i]);
            rec[u] = (ll)lo | ((ll)hi << 32);
        }
#pragma unroll
        for (int u = 0; u < 8; ++u) pos[u] = atomicAdd(&cur[bb[u]], 1);
#pragma unroll
        for (int u = 0; u < 8; ++u)
            if (pos[u] < (bb[u] + 1) * SLAB) edges[pos[u]] = rec[u];
    } else {
        for (int i = threadIdx.x; i < lim; i += 1024) {
            int r = rows[base + i];
            int b = r >> 7;
            unsigned int lo = ((unsigned int)cols[base + i]) | (((unsigned int)(r & 127)) << 17);
            unsigned int hi = __float_as_uint(vals[base + i]);
            int pos = atomicAdd(&cur[b], 1);
            if (pos < (b + 1) * SLAB) edges[pos] = (ll)lo | ((ll)hi << 32);
        }
    }
}

// LDS-staged in-place counting sort by row-within-bucket; pads each row's list to a
// multiple of 8 with zero-val records; emits row_start/counts (padded counts).
// hist & store phases batched 4-wide so LDS-atomic latency overlaps.
__global__ __launch_bounds__(512)
void bucket_sort_kernel(ll* __restrict__ edges, const int* __restrict__ gcursor,
                        int* __restrict__ row_start, int* __restrict__ counts) {
    __shared__ ll recL[SLAB];                       // 22 KB
    __shared__ int rcnt[RPB];
    __shared__ int pcnt[RPB];
    __shared__ int rcur[RPB];
    __shared__ int ssc[RPB];
    int b = blockIdx.x;
    int base = b * SLAB;
    int n = gcursor[b] - base;
    if (n > SLAB) n = SLAB;
    if (n < 0) n = 0;
    int t = threadIdx.x;
    if (t < RPB) rcnt[t] = 0;
    __syncthreads();
    {   // staged load + batched histogram
        ll rc[4]; int lr[4]; bool vld[4];
#pragma unroll
        for (int u = 0; u < 4; ++u) {
            int i = t + u * 512;
            vld[u] = (i < n);
            if (vld[u]) { rc[u] = edges[base + i]; recL[i] = rc[u]; lr[u] = (int)((rc[u] >> 17) & 127); }
        }
#pragma unroll
        for (int u = 0; u < 4; ++u) if (vld[u]) atomicAdd(&rcnt[lr[u]], 1);
        for (int i = t + 2048; i < n; i += 512) {
            ll rec = edges[base + i];
            recL[i] = rec;
            atomicAdd(&rcnt[(int)((rec >> 17) & 127)], 1);
        }
    }
    __syncthreads();
    if (t < RPB) pcnt[t] = (rcnt[t] + 7) & ~7;      // pad to multiple of 8
    __syncthreads();
    // inclusive scan of pcnt
    if (t < RPB) ssc[t] = pcnt[t];
    __syncthreads();
    for (int off = 1; off < RPB; off <<= 1) {
        int x = 0;
        if (t < RPB && t >= off) x = ssc[t - off];
        __syncthreads();
        if (t < RPB) ssc[t] += x;
        __syncthreads();
    }
    if (ssc[RPB - 1] > SLAB) {                      // overflow: fall back to unpadded
        __syncthreads();
        if (t < RPB) { pcnt[t] = rcnt[t]; ssc[t] = rcnt[t]; }
        __syncthreads();
        for (int off = 1; off < RPB; off <<= 1) {
            int x = 0;
            if (t < RPB && t >= off) x = ssc[t - off];
            __syncthreads();
            if (t < RPB) ssc[t] += x;
            __syncthreads();
        }
    }
    __syncthreads();
    if (t < RPB) {
        int ex = ssc[t] - pcnt[t];                  // exclusive (padded) start
        rcur[t] = ex;
        int v = b * RPB + t;
        if (v < NV) { row_start[v] = base + ex; counts[v] = pcnt[t]; }
    }
    __syncthreads();
    {   // batched placement
        ll rc[4]; int lr[4]; int pos[4]; bool vld[4];
#pragma unroll
        for (int u = 0; u < 4; ++u) {
            int i = t + u * 512;
            vld[u] = (i < n);
            if (vld[u]) { rc[u] = recL[i]; lr[u] = (int)((rc[u] >> 17) & 127); }
        }
#pragma unroll
        for (int u = 0; u < 4; ++u) if (vld[u]) pos[u] = atomicAdd(&rcur[lr[u]], 1);
#pragma unroll
        for (int u = 0; u < 4; ++u) if (vld[u]) edges[base + pos[u]] = rc[u];
        for (int i = t + 2048; i < n; i += 512) {
            ll rec = recL[i];
            int pos = atomicAdd(&rcur[(int)((rec >> 17) & 127)], 1);
            edges[base + pos] = rec;
        }
    }
    __syncthreads();
    // fill pad slots with zero records (col=0, val=0)
    if (t < RPB) {
        int start = ssc[t] - pcnt[t];
        for (int i = rcnt[t]; i < pcnt[t]; ++i)
            edges[base + start + i] = 0;
    }
}

// ---------------- bf16 conversion: inputs [B,V,F] -> xb [V, B*32] ----------------
// block 0 additionally initializes the slab cursors (runs before place in stream order)
__global__ void convert_x0_kernel(__hip_bfloat16* __restrict__ xb, const float* __restrict__ inputs,
                                  int* __restrict__ gcursor) {
    if (blockIdx.x == 0) {
        for (int i = threadIdx.x; i < NBUCK; i += 256) gcursor[i] = i * SLAB;
    }
    long i = (long)blockIdx.x * blockDim.x + threadIdx.x;
    if (i >= (long)NV * 64) return;
    int lane = (int)(i & 63);
    long v = i >> 6;
    int b = lane >> 5, f = lane & 31;
    xb[i] = __float2bfloat16(inputs[(long)b * NV * FIN + v * FIN + f]);
}

// ---------------- gather SpMM with fused recursion (bf16) ----------------
// one wave per row; lane = b*32 + f; x layout [V, 64]
// edge records via scalar loads (SGPRs); 16-deep main batch, 8-deep tail
__global__ __launch_bounds__(256)
void spmm_gather_kernel(__hip_bfloat16* __restrict__ xnext, const __hip_bfloat16* __restrict__ xcur,
                        const __hip_bfloat16* __restrict__ xprev,
                        const int* __restrict__ row_start, const int* __restrict__ counts,
                        const ll* __restrict__ edges, float alpha, float beta) {
    int r = blockIdx.x * (blockDim.x >> 6) + (threadIdx.x >> 6);
    int lane = threadIdx.x & 63;
    int s = __builtin_amdgcn_readfirstlane(row_start[r]);
    int cnt = __builtin_amdgcn_readfirstlane(counts[r]);
    const ll* ep = edges + s;
    float acc = 0.f;
    int j = 0;
    for (; j + 16 <= cnt; j += 16) {
        ll e[16];
        unsigned int g[16];
#pragma unroll
        for (int u = 0; u < 16; ++u) e[u] = ep[j + u];
#pragma unroll
        for (int u = 0; u < 16; ++u)
            g[u] = ((const unsigned short*)xcur)[(long)(e[u] & 0x1FFFF) * 64 + lane];
#pragma unroll
        for (int u = 0; u < 16; ++u)
            acc = fmaf(__uint_as_float((unsigned int)((unsigned long long)e[u] >> 32)),
                       __uint_as_float((unsigned int)g[u] << 16), acc);
    }
    if (j + 8 <= cnt) {
        ll e[8];
        unsigned int g[8];
#pragma unroll
        for (int u = 0; u < 8; ++u) e[u] = ep[j + u];
#pragma unroll
        for (int u = 0; u < 8; ++u)
            g[u] = ((const unsigned short*)xcur)[(long)(e[u] & 0x1FFFF) * 64 + lane];
#pragma unroll
        for (int u = 0; u < 8; ++u)
            acc = fmaf(__uint_as_float((unsigned int)((unsigned long long)e[u] >> 32)),
                       __uint_as_float((unsigned int)g[u] << 16), acc);
        j += 8;
    }
    for (; j < cnt; ++j) {   // only runs in (statistically impossible) unpadded fallback
        ll e0 = ep[j];
        unsigned int g0 = ((const unsigned short*)xcur)[(long)(e0 & 0x1FFFF) * 64 + lane];
        acc = fmaf(__uint_as_float((unsigned int)((unsigned long long)e0 >> 32)),
                   __uint_as_float(g0 << 16), acc);
    }
    long o = (long)r * 64 + lane;
    float res = alpha * acc;
    if (beta != 0.f) res += beta * __bfloat162float(xprev[o]);
    xnext[o] = __float2bfloat16(res);
}

// ---------------- fused final einsum: out = bias + sum_k xk @ W[:,k,:] ----------------
// grid (x = (v,b) / 256, y = output half); thread = (v,b), 16 outputs, 64B line write
__global__ __launch_bounds__(256)
void final_gemm_kernel(float* __restrict__ out,
                       const __hip_bfloat16* __restrict__ xb0,
                       const __hip_bfloat16* __restrict__ xb1,
                       const __hip_bfloat16* __restrict__ xb2,
                       const __hip_bfloat16* __restrict__ xb3,
                       const float* __restrict__ weight,
                       const float* __restrict__ bias) {
    int t = blockIdx.x * blockDim.x + threadIdx.x;
    if (t >= NV * NB) return;
    int oh = blockIdx.y * 16;            // output half offset
    int v = t >> 1, b = t & 1;
    float acc[16];
#pragma unroll
    for (int o = 0; o < 16; ++o) acc[o] = bias[oh + o];
    for (int k = 0; k < NK; ++k) {
        const __hip_bfloat16* xr = (k == 0) ? xb0 : (k == 1) ? xb1 : (k == 2) ? xb2 : xb3;
        const uint4* xp = (const uint4*)(xr + (long)v * 64 + b * 32);
        uint4 q0 = xp[0], q1 = xp[1], q2 = xp[2], q3 = xp[3];
        unsigned int qq[16] = {q0.x, q0.y, q0.z, q0.w, q1.x, q1.y, q1.z, q1.w,
                               q2.x, q2.y, q2.z, q2.w, q3.x, q3.y, q3.z, q3.w};
        const float* wk = weight + k * FOUT + oh;
#pragma unroll
        for (int i = 0; i < 16; ++i) {
            float xlo = __uint_as_float(qq[i] << 16);
            float xhi = __uint_as_float(qq[i] & 0xffff0000u);
            const float* w0 = wk + (2 * i) * (NK * FOUT);
            const float* w1 = wk + (2 * i + 1) * (NK * FOUT);
#pragma unroll
            for (int o = 0; o < 16; ++o) {
                acc[o] = fmaf(xlo, w0[o], acc[o]);
                acc[o] = fmaf(xhi, w1[o], acc[o]);
            }
        }
    }
    float* op = out + (long)b * NV * FOUT + (long)v * FOUT + oh;
#pragma unroll
    for (int o = 0; o < 16; ++o) op[o] = acc[o];
}

extern "C" void kernel_launch(void* const* d_in, const int* in_sizes, int n_in,
                              void* d_out, int out_size, void* d_ws, size_t ws_size,
                              hipStream_t stream) {
    const float* inputs = (const float*)d_in[0];
    const int*   rows   = (const int*)d_in[1];
    const int*   cols   = (const int*)d_in[2];
    const float* vals   = (const float*)d_in[3];
    const float* weight = (const float*)d_in[4];
    const float* bias   = (const float*)d_in[5];
    float* out = (float*)d_out;

    const long n = (long)NB * NV * FIN;            // 6.4M
    const int gG = (NB * NV) / 8;
    const int gChunk = (NE + CHUNK - 1) / CHUNK;   // 196
    const int gRow = NV / 4;                       // 25000 (4 waves/block, 1 row/wave)
    const int gConv = (int)(((long)NV * 64 + 255) / 256);
    const int gGemm = (NV * NB + 255) / 256;       // 782

    // ws layout: [gcursor 1024][row_start NV][counts NV] [edges NBUCK*SLAB] [xb0..xb3]
    int* gcursor   = (int*)d_ws;                   // [1024]
    int* row_start = gcursor + 1024;               // [NV]
    int* counts    = row_start + NV;               // [NV]
    ll* edges      = (ll*)(counts + NV);           // [NBUCK*SLAB]
    size_t off = (size_t)((char*)(edges + (long)NBUCK * SLAB) - (char*)d_ws);
    off = (off + 255) & ~(size_t)255;
    __hip_bfloat16* xb0 = (__hip_bfloat16*)((char*)d_ws + off);
    __hip_bfloat16* xb1 = xb0 + (long)NV * 64;
    __hip_bfloat16* xb2 = xb1 + (long)NV * 64;
    __hip_bfloat16* xb3 = xb2 + (long)NV * 64;
    size_t need = off + 4 * (size_t)NV * 64 * sizeof(__hip_bfloat16);

    if (ws_size < need) {
        // fallback: round-0 atomic scatter path
        float* fA = (float*)d_ws;
        float* fB = fA + n;
        const int gNf = (int)((n + 255) / 256);
        const int gEf = (NE * 32 + 255) / 256;
        term_gemm_kernel<<<gG, 256, 0, stream>>>(out, inputs, weight, bias, 0, 1);
        scale_init_kernel<<<gNf, 256, 0, stream>>>(fA, inputs, 0.f, (int)n);
        spmm_scatter_kernel<<<gEf, 256, 0, stream>>>(fA, inputs, rows, cols, vals, 1.f);
        term_gemm_kernel<<<gG, 256, 0, stream>>>(out, fA, weight, bias, 1, 0);
        scale_init_kernel<<<gNf, 256, 0, stream>>>(fB, inputs, -1.f, (int)n);
        spmm_scatter_kernel<<<gEf, 256, 0, stream>>>(fB, fA, rows, cols, vals, 2.f);
        term_gemm_kernel<<<gG, 256, 0, stream>>>(out, fB, weight, bias, 2, 0);
        scale_init_kernel<<<gNf, 256, 0, stream>>>(fA, fA, -1.f, (int)n);
        spmm_scatter_kernel<<<gEf, 256, 0, stream>>>(fA, fB, rows, cols, vals, 2.f);
        term_gemm_kernel<<<gG, 256, 0, stream>>>(out, fA, weight, bias, 3, 0);
        return;
    }

    // convert first (block 0 also inits slab cursors), then slab CSR build
    convert_x0_kernel<<<gConv, 256, 0, stream>>>(xb0, inputs, gcursor);
    bucket_place_kernel<<<gChunk, 1024, 0, stream>>>(rows, cols, vals, gcursor, edges);
    bucket_sort_kernel<<<NBUCK, 512, 0, stream>>>(edges, gcursor, row_start, counts);

    // recursion
    spmm_gather_kernel<<<gRow, 256, 0, stream>>>(xb1, xb0, nullptr, row_start, counts,
                                                 edges, 1.f, 0.f);
    spmm_gather_kernel<<<gRow, 256, 0, stream>>>(xb2, xb1, xb0, row_start, counts,
                                                 edges, 2.f, -1.f);
    spmm_gather_kernel<<<gRow, 256, 0, stream>>>(xb3, xb2, xb1, row_start, counts,
                                                 edges, 2.f, -1.f);

    // fused einsum over all 4 terms (y-dim splits the 32 outputs into two halves)
    final_gemm_kernel<<<dim3(gGemm, 2), 256, 0, stream>>>(out, xb0, xb1, xb2, xb3,
                                                          weight, bias);
}

// Round 16
// 182.351 us; speedup vs baseline: 1.0972x; 1.0102x over previous
//
#include <hip/hip_runtime.h>
#include <hip/hip_bf16.h>

#define NV 100000
#define NE 1600000
#define NB 2
#define FIN 32
#define NK 4
#define FOUT 32

#define RPB 128                          // rows per bucket
#define NBUCK ((NV + RPB - 1) / RPB)     // 782
#define SLAB 2816                        // slab capacity (mean padded 2494, ~6 sigma slack)
#define CHUNK 8192                       // edges per place block (196 place blocks x 1024 thr)
#define GCHUNK ((NE + CHUNK - 1) / CHUNK)          // 196
#define GCONV (((long)NV * 64 + 1023) / 1024)      // 6250

typedef long long ll;

// ---------------- fallback (round-0) kernels ----------------

__global__ void scale_init_kernel(float* __restrict__ dst, const float* __restrict__ src,
                                  float alpha, int n) {
    int i = blockIdx.x * blockDim.x + threadIdx.x;
    if (i < n) dst[i] = alpha * src[i];
}

__global__ void spmm_scatter_kernel(float* __restrict__ y, const float* __restrict__ x,
                                    const int* __restrict__ rows, const int* __restrict__ cols,
                                    const float* __restrict__ vals, float scale) {
    long tid = (long)blockIdx.x * blockDim.x + threadIdx.x;
    int e = (int)(tid >> 5);
    int f = (int)(tid & 31);
    if (e >= NE) return;
    int r = rows[e];
    int c = cols[e];
    float v = scale * vals[e];
#pragma unroll
    for (int b = 0; b < NB; ++b) {
        float g = x[(long)b * NV * FIN + (long)c * FIN + f];
        atomicAdd(&y[(long)b * NV * FIN + (long)r * FIN + f], v * g);
    }
}

__global__ void term_gemm_kernel(float* __restrict__ out, const float* __restrict__ x,
                                 const float* __restrict__ weight, const float* __restrict__ bias,
                                 int k, int first) {
    __shared__ float Wl[FIN][FOUT];
    __shared__ float Xl[8][FIN];
    int tid = threadIdx.x;
    for (int i = tid; i < FIN * FOUT; i += 256) {
        int f = i >> 5, o = i & 31;
        Wl[f][o] = weight[f * (NK * FOUT) + k * FOUT + o];
    }
    long rbase = (long)blockIdx.x * 8;
    for (int i = tid; i < 8 * FIN; i += 256) {
        int rv = i >> 5, f = i & 31;
        Xl[rv][f] = x[(rbase + rv) * FIN + f];
    }
    __syncthreads();
    int rv = tid >> 5, o = tid & 31;
    float acc = 0.f;
#pragma unroll
    for (int f = 0; f < FIN; ++f) acc += Xl[rv][f] * Wl[f][o];
    long r = rbase + rv;
    if (first) out[r * FOUT + o] = acc + bias[o];
    else       out[r * FOUT + o] += acc;
}

// ---------------- fused convert + slab place ----------------
// edge record (8B): bits 0..16 = col, bits 17..23 = row-within-bucket, high 32 = val bits
// gcursor holds OFFSETS within each slab (0-initialized via memsetAsync).
// blocks [0, GCHUNK) do edge placement; blocks [GCHUNK, GCHUNK+GCONV) do x0 bf16 convert.
__global__ __launch_bounds__(1024)
void convert_place_kernel(const int* __restrict__ rows, const int* __restrict__ cols,
                          const float* __restrict__ vals, int* __restrict__ gcursor,
                          ll* __restrict__ edges,
                          __hip_bfloat16* __restrict__ xb, const float* __restrict__ inputs) {
    if (blockIdx.x >= GCHUNK) {
        // ---- convert: inputs [B,V,F] -> xb [V, B*32] ----
        long i = (long)(blockIdx.x - GCHUNK) * 1024 + threadIdx.x;
        if (i < (long)NV * 64) {
            int lane = (int)(i & 63);
            long v = i >> 6;
            int b = lane >> 5, f = lane & 31;
            xb[i] = __float2bfloat16(inputs[(long)b * NV * FIN + v * FIN + f]);
        }
        return;
    }
    __shared__ int cnt[NBUCK];
    __shared__ int cur[NBUCK];
    for (int i = threadIdx.x; i < NBUCK; i += 1024) cnt[i] = 0;
    __syncthreads();
    long base = (long)blockIdx.x * CHUNK;
    int lim = (base + CHUNK <= NE) ? CHUNK : (int)(NE - base);
    for (int i = threadIdx.x; i < lim; i += 1024)
        atomicAdd(&cnt[rows[base + i] >> 7], 1);
    __syncthreads();
    // reserve a contiguous range per bucket for this block (cursor = offset in slab)
    for (int i = threadIdx.x; i < NBUCK; i += 1024)
        cur[i] = cnt[i] ? (i * SLAB + atomicAdd(&gcursor[i], cnt[i])) : 0;
    __syncthreads();
    if (lim == CHUNK) {
        // fast path: 8 edges/thread, batch atomics so their latency overlaps
        int bb[8]; ll rec[8]; int pos[8];
#pragma unroll
        for (int u = 0; u < 8; ++u) {
            int i = threadIdx.x + u * 1024;
            int r = rows[base + i];
            bb[u] = r >> 7;
            unsigned int lo = ((unsigned int)cols[base + i]) | (((unsigned int)(r & 127)) << 17);
            unsigned int hi = __float_as_uint(vals[base + i]);
            rec[u] = (ll)lo | ((ll)hi << 32);
        }
#pragma unroll
        for (int u = 0; u < 8; ++u) pos[u] = atomicAdd(&cur[bb[u]], 1);
#pragma unroll
        for (int u = 0; u < 8; ++u)
            if (pos[u] < (bb[u] + 1) * SLAB) edges[pos[u]] = rec[u];
    } else {
        for (int i = threadIdx.x; i < lim; i += 1024) {
            int r = rows[base + i];
            int b = r >> 7;
            unsigned int lo = ((unsigned int)cols[base + i]) | (((unsigned int)(r & 127)) << 17);
            unsigned int hi = __float_as_uint(vals[base + i]);
            int pos = atomicAdd(&cur[b], 1);
            if (pos < (b + 1) * SLAB) edges[pos] = (ll)lo | ((ll)hi << 32);
        }
    }
}

// LDS-staged in-place counting sort by row-within-bucket; pads each row's list to a
// multiple of 8 with zero-val records; emits row_start/counts (padded counts).
__global__ __launch_bounds__(512)
void bucket_sort_kernel(ll* __restrict__ edges, const int* __restrict__ gcursor,
                        int* __restrict__ row_start, int* __restrict__ counts) {
    __shared__ ll recL[SLAB];                       // 22 KB
    __shared__ int rcnt[RPB];
    __shared__ int pcnt[RPB];
    __shared__ int rcur[RPB];
    __shared__ int ssc[RPB];
    int b = blockIdx.x;
    int base = b * SLAB;
    int n = gcursor[b];                             // cursor is slab-relative count
    if (n > SLAB) n = SLAB;
    if (n < 0) n = 0;
    int t = threadIdx.x;
    if (t < RPB) rcnt[t] = 0;
    __syncthreads();
    {   // staged load + batched histogram
        ll rc[4]; int lr[4]; bool vld[4];
#pragma unroll
        for (int u = 0; u < 4; ++u) {
            int i = t + u * 512;
            vld[u] = (i < n);
            if (vld[u]) { rc[u] = edges[base + i]; recL[i] = rc[u]; lr[u] = (int)((rc[u] >> 17) & 127); }
        }
#pragma unroll
        for (int u = 0; u < 4; ++u) if (vld[u]) atomicAdd(&rcnt[lr[u]], 1);
        for (int i = t + 2048; i < n; i += 512) {
            ll rec = edges[base + i];
            recL[i] = rec;
            atomicAdd(&rcnt[(int)((rec >> 17) & 127)], 1);
        }
    }
    __syncthreads();
    if (t < RPB) pcnt[t] = (rcnt[t] + 7) & ~7;      // pad to multiple of 8
    __syncthreads();
    // inclusive scan of pcnt
    if (t < RPB) ssc[t] = pcnt[t];
    __syncthreads();
    for (int off = 1; off < RPB; off <<= 1) {
        int x = 0;
        if (t < RPB && t >= off) x = ssc[t - off];
        __syncthreads();
        if (t < RPB) ssc[t] += x;
        __syncthreads();
    }
    if (ssc[RPB - 1] > SLAB) {                      // overflow: fall back to unpadded
        __syncthreads();
        if (t < RPB) { pcnt[t] = rcnt[t]; ssc[t] = rcnt[t]; }
        __syncthreads();
        for (int off = 1; off < RPB; off <<= 1) {
            int x = 0;
            if (t < RPB && t >= off) x = ssc[t - off];
            __syncthreads();
            if (t < RPB) ssc[t] += x;
            __syncthreads();
        }
    }
    __syncthreads();
    if (t < RPB) {
        int ex = ssc[t] - pcnt[t];                  // exclusive (padded) start
        rcur[t] = ex;
        int v = b * RPB + t;
        if (v < NV) { row_start[v] = base + ex; counts[v] = pcnt[t]; }
    }
    __syncthreads();
    {   // batched placement
        ll rc[4]; int lr[4]; int pos[4]; bool vld[4];
#pragma unroll
        for (int u = 0; u < 4; ++u) {
            int i = t + u * 512;
            vld[u] = (i < n);
            if (vld[u]) { rc[u] = recL[i]; lr[u] = (int)((rc[u] >> 17) & 127); }
        }
#pragma unroll
        for (int u = 0; u < 4; ++u) if (vld[u]) pos[u] = atomicAdd(&rcur[lr[u]], 1);
#pragma unroll
        for (int u = 0; u < 4; ++u) if (vld[u]) edges[base + pos[u]] = rc[u];
        for (int i = t + 2048; i < n; i += 512) {
            ll rec = recL[i];
            int pos = atomicAdd(&rcur[(int)((rec >> 17) & 127)], 1);
            edges[base + pos] = rec;
        }
    }
    __syncthreads();
    // fill pad slots with zero records (col=0, val=0)
    if (t < RPB) {
        int start = ssc[t] - pcnt[t];
        for (int i = rcnt[t]; i < pcnt[t]; ++i)
            edges[base + start + i] = 0;
    }
}

// ---------------- gather SpMM with fused recursion (bf16) ----------------
// one wave per row; lane = b*32 + f; x layout [V, 64]
// edge records via scalar loads (SGPRs); 16-deep main batch, 8-deep tail
__global__ __launch_bounds__(256)
void spmm_gather_kernel(__hip_bfloat16* __restrict__ xnext, const __hip_bfloat16* __restrict__ xcur,
                        const __hip_bfloat16* __restrict__ xprev,
                        const int* __restrict__ row_start, const int* __restrict__ counts,
                        const ll* __restrict__ edges, float alpha, float beta) {
    int r = blockIdx.x * (blockDim.x >> 6) + (threadIdx.x >> 6);
    int lane = threadIdx.x & 63;
    int s = __builtin_amdgcn_readfirstlane(row_start[r]);
    int cnt = __builtin_amdgcn_readfirstlane(counts[r]);
    const ll* ep = edges + s;
    float acc = 0.f;
    int j = 0;
    for (; j + 16 <= cnt; j += 16) {
        ll e[16];
        unsigned int g[16];
#pragma unroll
        for (int u = 0; u < 16; ++u) e[u] = ep[j + u];
#pragma unroll
        for (int u = 0; u < 16; ++u)
            g[u] = ((const unsigned short*)xcur)[(long)(e[u] & 0x1FFFF) * 64 + lane];
#pragma unroll
        for (int u = 0; u < 16; ++u)
            acc = fmaf(__uint_as_float((unsigned int)((unsigned long long)e[u] >> 32)),
                       __uint_as_float((unsigned int)g[u] << 16), acc);
    }
    if (j + 8 <= cnt) {
        ll e[8];
        unsigned int g[8];
#pragma unroll
        for (int u = 0; u < 8; ++u) e[u] = ep[j + u];
#pragma unroll
        for (int u = 0; u < 8; ++u)
            g[u] = ((const unsigned short*)xcur)[(long)(e[u] & 0x1FFFF) * 64 + lane];
#pragma unroll
        for (int u = 0; u < 8; ++u)
            acc = fmaf(__uint_as_float((unsigned int)((unsigned long long)e[u] >> 32)),
                       __uint_as_float((unsigned int)g[u] << 16), acc);
        j += 8;
    }
    for (; j < cnt; ++j) {   // only runs in (statistically impossible) unpadded fallback
        ll e0 = ep[j];
        unsigned int g0 = ((const unsigned short*)xcur)[(long)(e0 & 0x1FFFF) * 64 + lane];
        acc = fmaf(__uint_as_float((unsigned int)((unsigned long long)e0 >> 32)),
                   __uint_as_float(g0 << 16), acc);
    }
    long o = (long)r * 64 + lane;
    float res = alpha * acc;
    if (beta != 0.f) res += beta * __bfloat162float(xprev[o]);
    xnext[o] = __float2bfloat16(res);
}

// ---------------- fused final einsum: out = bias + sum_k xk @ W[:,k,:] ----------------
// grid (x = (v,b) / 256, y = output half); thread = (v,b), 16 outputs, 64B line write
__global__ __launch_bounds__(256)
void final_gemm_kernel(float* __restrict__ out,
                       const __hip_bfloat16* __restrict__ xb0,
                       const __hip_bfloat16* __restrict__ xb1,
                       const __hip_bfloat16* __restrict__ xb2,
                       const __hip_bfloat16* __restrict__ xb3,
                       const float* __restrict__ weight,
                       const float* __restrict__ bias) {
    int t = blockIdx.x * blockDim.x + threadIdx.x;
    if (t >= NV * NB) return;
    int oh = blockIdx.y * 16;            // output half offset
    int v = t >> 1, b = t & 1;
    float acc[16];
#pragma unroll
    for (int o = 0; o < 16; ++o) acc[o] = bias[oh + o];
    for (int k = 0; k < NK; ++k) {
        const __hip_bfloat16* xr = (k == 0) ? xb0 : (k == 1) ? xb1 : (k == 2) ? xb2 : xb3;
        const uint4* xp = (const uint4*)(xr + (long)v * 64 + b * 32);
        uint4 q0 = xp[0], q1 = xp[1], q2 = xp[2], q3 = xp[3];
        unsigned int qq[16] = {q0.x, q0.y, q0.z, q0.w, q1.x, q1.y, q1.z, q1.w,
                               q2.x, q2.y, q2.z, q2.w, q3.x, q3.y, q3.z, q3.w};
        const float* wk = weight + k * FOUT + oh;
#pragma unroll
        for (int i = 0; i < 16; ++i) {
            float xlo = __uint_as_float(qq[i] << 16);
            float xhi = __uint_as_float(qq[i] & 0xffff0000u);
            const float* w0 = wk + (2 * i) * (NK * FOUT);
            const float* w1 = wk + (2 * i + 1) * (NK * FOUT);
#pragma unroll
            for (int o = 0; o < 16; ++o) {
                acc[o] = fmaf(xlo, w0[o], acc[o]);
                acc[o] = fmaf(xhi, w1[o], acc[o]);
            }
        }
    }
    float* op = out + (long)b * NV * FOUT + (long)v * FOUT + oh;
#pragma unroll
    for (int o = 0; o < 16; ++o) op[o] = acc[o];
}

extern "C" void kernel_launch(void* const* d_in, const int* in_sizes, int n_in,
                              void* d_out, int out_size, void* d_ws, size_t ws_size,
                              hipStream_t stream) {
    const float* inputs = (const float*)d_in[0];
    const int*   rows   = (const int*)d_in[1];
    const int*   cols   = (const int*)d_in[2];
    const float* vals   = (const float*)d_in[3];
    const float* weight = (const float*)d_in[4];
    const float* bias   = (const float*)d_in[5];
    float* out = (float*)d_out;

    const long n = (long)NB * NV * FIN;            // 6.4M
    const int gG = (NB * NV) / 8;
    const int gRow = NV / 4;                       // 25000 (4 waves/block, 1 row/wave)
    const int gGemm = (NV * NB + 255) / 256;       // 782
    const int gFused = GCHUNK + (int)GCONV;        // 196 place + 6250 convert

    // ws layout: [gcursor 1024][row_start NV][counts NV] [edges NBUCK*SLAB] [xb0..xb3]
    int* gcursor   = (int*)d_ws;                   // [1024] slab-relative offsets
    int* row_start = gcursor + 1024;               // [NV]
    int* counts    = row_start + NV;               // [NV]
    ll* edges      = (ll*)(counts + NV);           // [NBUCK*SLAB]
    size_t off = (size_t)((char*)(edges + (long)NBUCK * SLAB) - (char*)d_ws);
    off = (off + 255) & ~(size_t)255;
    __hip_bfloat16* xb0 = (__hip_bfloat16*)((char*)d_ws + off);
    __hip_bfloat16* xb1 = xb0 + (long)NV * 64;
    __hip_bfloat16* xb2 = xb1 + (long)NV * 64;
    __hip_bfloat16* xb3 = xb2 + (long)NV * 64;
    size_t need = off + 4 * (size_t)NV * 64 * sizeof(__hip_bfloat16);

    if (ws_size < need) {
        // fallback: round-0 atomic scatter path
        float* fA = (float*)d_ws;
        float* fB = fA + n;
        const int gNf = (int)((n + 255) / 256);
        const int gEf = (NE * 32 + 255) / 256;
        term_gemm_kernel<<<gG, 256, 0, stream>>>(out, inputs, weight, bias, 0, 1);
        scale_init_kernel<<<gNf, 256, 0, stream>>>(fA, inputs, 0.f, (int)n);
        spmm_scatter_kernel<<<gEf, 256, 0, stream>>>(fA, inputs, rows, cols, vals, 1.f);
        term_gemm_kernel<<<gG, 256, 0, stream>>>(out, fA, weight, bias, 1, 0);
        scale_init_kernel<<<gNf, 256, 0, stream>>>(fB, inputs, -1.f, (int)n);
        spmm_scatter_kernel<<<gEf, 256, 0, stream>>>(fB, fA, rows, cols, vals, 2.f);
        term_gemm_kernel<<<gG, 256, 0, stream>>>(out, fB, weight, bias, 2, 0);
        scale_init_kernel<<<gNf, 256, 0, stream>>>(fA, fA, -1.f, (int)n);
        spmm_scatter_kernel<<<gEf, 256, 0, stream>>>(fA, fB, rows, cols, vals, 2.f);
        term_gemm_kernel<<<gG, 256, 0, stream>>>(out, fA, weight, bias, 3, 0);
        return;
    }

    // cursors = slab-relative offsets, zero-init; fused convert+place; per-bucket sort
    hipMemsetAsync(gcursor, 0, (size_t)NBUCK * sizeof(int), stream);
    convert_place_kernel<<<gFused, 1024, 0, stream>>>(rows, cols, vals, gcursor, edges,
                                                      xb0, inputs);
    bucket_sort_kernel<<<NBUCK, 512, 0, stream>>>(edges, gcursor, row_start, counts);

    // recursion
    spmm_gather_kernel<<<gRow, 256, 0, stream>>>(xb1, xb0, nullptr, row_start, counts,
                                                 edges, 1.f, 0.f);
    spmm_gather_kernel<<<gRow, 256, 0, stream>>>(xb2, xb1, xb0, row_start, counts,
                                                 edges, 2.f, -1.f);
    spmm_gather_kernel<<<gRow, 256, 0, stream>>>(xb3, xb2, xb1, row_start, counts,
                                                 edges, 2.f, -1.f);

    // fused einsum over all 4 terms (y-dim splits the 32 outputs into two halves)
    final_gemm_kernel<<<dim3(gGemm, 2), 256, 0, stream>>>(out, xb0, xb1, xb2, xb3,
                                                          weight, bias);
}